// Round 4
// baseline (4342.260 us; speedup 1.0000x reference)
//
#include <hip/hip_runtime.h>

#define Bn  16
#define Ln  256
#define D0n 64
#define Hn  128
#define H4n 512
#define Kn  512
#define BLn 4096   // Bn*Ln

typedef float f4 __attribute__((ext_vector_type(4)));

__device__ __forceinline__ float sigf(float x) { return 1.0f / (1.0f + expf(-x)); }

__device__ __forceinline__ float fma4v(f4 w, f4 x, float acc) {
    acc = fmaf(w.x, x.x, acc);
    acc = fmaf(w.y, x.y, acc);
    acc = fmaf(w.z, x.z, acc);
    acc = fmaf(w.w, x.w, acc);
    return acc;
}

// ILP-4 dot product (n4 must be a multiple of 4)
__device__ __forceinline__ float dotn(const f4* __restrict__ a,
                                      const f4* __restrict__ w, int n4) {
    float a0 = 0.f, a1 = 0.f, a2 = 0.f, a3 = 0.f;
    for (int i = 0; i < n4; i += 4) {
        a0 = fma4v(a[i], w[i], a0);
        a1 = fma4v(a[i + 1], w[i + 1], a1);
        a2 = fma4v(a[i + 2], w[i + 2], a2);
        a3 = fma4v(a[i + 3], w[i + 3], a3);
    }
    return (a0 + a1) + (a2 + a3);
}

// -------- generic Linear: Y[r][c] = scale*(X[r].W[c]) + b[c], opt relu --------
__global__ void k_lin(const float* __restrict__ X, const float* __restrict__ W,
                      const float* __restrict__ b, float* __restrict__ Y,
                      int rows, int in_dim, int out_dim, int do_relu, float scale) {
    int idx = blockIdx.x * blockDim.x + threadIdx.x;
    if (idx >= rows * out_dim) return;
    int r = idx / out_dim, c = idx % out_dim;
    const f4* x4 = (const f4*)(X + (size_t)r * in_dim);
    const f4* w4 = (const f4*)(W + (size_t)c * in_dim);
    float acc = scale * dotn(x4, w4, in_dim >> 2);
    if (b) acc += b[c];
    if (do_relu) acc = fmaxf(acc, 0.f);
    Y[idx] = acc;
}

// -------- enc_lin2 with concatenated [hf, hb] input --------
__global__ void k_enc_lin2(const float* __restrict__ hf, const float* __restrict__ hb,
                           const float* __restrict__ W2, const float* __restrict__ b2,
                           float* __restrict__ ze) {
    int idx = blockIdx.x * blockDim.x + threadIdx.x;
    if (idx >= BLn * Hn) return;
    int r = idx / Hn, c = idx % Hn;
    const float* w = W2 + (size_t)c * (2 * Hn);
    float acc = b2[c];
    acc += dotn((const f4*)(hf + (size_t)r * Hn), (const f4*)w, Hn >> 2);
    acc += dotn((const f4*)(hb + (size_t)r * Hn), (const f4*)(w + Hn), Hn >> 2);
    ze[idx] = acc;
}

// -------- small transpose: out[c][r] = in[r][c] --------
__global__ void k_transpose(const float* __restrict__ in, float* __restrict__ out,
                            int R, int C) {
    int idx = blockIdx.x * blockDim.x + threadIdx.x;
    if (idx >= R * C) return;
    int c = idx / R, r = idx % R;
    out[idx] = in[(size_t)r * C + c];
}

// -------- rearrange [512][32] f4 row-major -> f4-major [32][512] --------
__global__ void k_rearr(const f4* __restrict__ in, f4* __restrict__ out) {
    int idx = blockIdx.x * blockDim.x + threadIdx.x;   // 16384
    if (idx >= 16384) return;
    int f = idx >> 9, row = idx & 511;
    out[idx] = in[(size_t)row * 32 + f];
}

// -------- cst[p] = scale*(bq . kp[p]) + (mask[p]==0 ? -1e9 : 0) --------
__global__ void k_cst(const float* __restrict__ kp, const float* __restrict__ bq,
                      const float* __restrict__ mask, float* __restrict__ cst) {
    int p = blockIdx.x * blockDim.x + threadIdx.x;
    if (p >= BLn) return;
    float a = dotn((const f4*)bq, (const f4*)(kp + (size_t)p * Hn), Hn >> 2);
    cst[p] = a * 0.088388347648318447f + (mask[p] == 0.f ? -1e9f : 0.f);
}

// -------- LSTM scan: 1024 thr, 2 threads per gate row, pinned half-row Whh ----
__global__ __launch_bounds__(1024)
void k_lstm_scan(const float* __restrict__ xWf, const float* __restrict__ xWb,
                 const float* __restrict__ Whh_f, const float* __restrict__ Whh_b,
                 float* __restrict__ hf, float* __restrict__ hb) {
    const int b   = blockIdx.x & 15;
    const int rev = blockIdx.x >> 4;
    const int tid = threadIdx.x;          // 0..1023
    const int row  = tid >> 1;            // gate row 0..511
    const int half = tid & 1;             // which 64-elem half of h
    const float* xW  = rev ? xWb : xWf;
    const float* Whh = rev ? Whh_b : Whh_f;
    float*       ho  = rev ? hb  : hf;

    __shared__ __align__(16) float h_s[Hn];
    __shared__ __align__(16) float g_s[H4n];

    float c_reg = 0.f;
    if (tid < Hn) h_s[tid] = 0.f;

    // resident HALF-row of Whh: 16 f4 = 64 VGPR, pinned so it can't be sunk
    f4 w[16];
    {
        const f4* p = (const f4*)(Whh + (size_t)row * Hn + half * 64);
#pragma unroll
        for (int i = 0; i < 16; ++i) w[i] = p[i];
#pragma unroll
        for (int i = 0; i < 16; ++i) asm volatile("" : "+v"(w[i]));
    }
    const int t0 = rev ? (Ln - 1) : 0;
    float xw_v = (half == 0) ? xW[((size_t)b * Ln + t0) * H4n + row] : 0.f;
    __syncthreads();

    for (int s = 0; s < Ln; ++s) {
        const int t = rev ? (Ln - 1 - s) : s;
        float xw_n = 0.f;
        if (half == 0 && s + 1 < Ln) {
            int tn = rev ? (Ln - 2 - s) : (s + 1);
            xw_n = xW[((size_t)b * Ln + tn) * H4n + row];
        }
        const f4* hh = (const f4*)(h_s + half * 64);
        float a0 = 0.f, a1 = 0.f, a2 = 0.f, a3 = 0.f;
#pragma unroll
        for (int i = 0; i < 16; i += 4) {
            a0 = fma4v(w[i], hh[i], a0);
            a1 = fma4v(w[i + 1], hh[i + 1], a1);
            a2 = fma4v(w[i + 2], hh[i + 2], a2);
            a3 = fma4v(w[i + 3], hh[i + 3], a3);
        }
        float acc = (a0 + a1) + (a2 + a3);
        acc += __shfl_xor(acc, 1);
        if (half == 0) g_s[row] = acc + xw_v;
        __syncthreads();
        if (tid < Hn) {
            float ig = sigf(g_s[tid]);
            float fg = sigf(g_s[Hn + tid]);
            float gg = tanhf(g_s[2 * Hn + tid]);
            float og = sigf(g_s[3 * Hn + tid]);
            c_reg = fg * c_reg + ig * gg;
            float hv = og * tanhf(c_reg);
            h_s[tid] = hv;
            ho[((size_t)b * Ln + t) * Hn + tid] = hv;
        }
        __syncthreads();
        xw_v = xw_n;
    }
}

// -------- codebook squared norms --------
__global__ void k_codenorm(const float* __restrict__ emb, float* __restrict__ c2) {
    int k = blockIdx.x * blockDim.x + threadIdx.x;
    if (k >= Kn) return;
    const f4* e4 = (const f4*)(emb + (size_t)k * Hn);
    float acc = 0.f;
    for (int i = 0; i < Hn / 4; ++i) {
        f4 v = e4[i];
        acc = fmaf(v.x, v.x, acc); acc = fmaf(v.y, v.y, acc);
        acc = fmaf(v.z, v.z, acc); acc = fmaf(v.w, v.w, acc);
    }
    c2[k] = acc;
}

// -------- VQ: argmin_k (||e_k||^2 - 2 ze.e_k), first-index tie-break --------
__global__ __launch_bounds__(256)
void k_vq(const float* __restrict__ ze, const float* __restrict__ emb,
          const float* __restrict__ c2, float* __restrict__ zq) {
    const int p = blockIdx.x;           // b*L + l
    const int tid = threadIdx.x;        // 256
    __shared__ __align__(16) float z_s[Hn];
    __shared__ float vals[256];
    __shared__ int   idxs[256];
    if (tid < Hn) z_s[tid] = ze[(size_t)p * Hn + tid];
    __syncthreads();

    float best = 3.0e38f; int bidx = 0;
    for (int k = tid; k < Kn; k += 256) {
        float d = c2[k] - 2.f * dotn((const f4*)z_s,
                                     (const f4*)(emb + (size_t)k * Hn), Hn >> 2);
        if (d < best) { best = d; bidx = k; }   // strict <  => first occurrence
    }
    vals[tid] = best; idxs[tid] = bidx;
    __syncthreads();
    for (int s = 128; s > 0; s >>= 1) {
        if (tid < s) {
            float v2 = vals[tid + s]; int i2 = idxs[tid + s];
            if (v2 < vals[tid] || (v2 == vals[tid] && i2 < idxs[tid])) {
                vals[tid] = v2; idxs[tid] = i2;
            }
        }
        __syncthreads();
    }
    const int nearest = idxs[0];
    if (tid < Hn) zq[(size_t)p * Hn + tid] = emb[(size_t)nearest * Hn + tid];
}

// -------- autoregressive decoder: 16 blocks x 512 thr ------------------------
// Persistent (PINNED) VGPRs: whr (Whh row, 128v) + vwr (VW' slice, 32v).
// KQ in LDS (XOR-swizzled). Streamed per step: W1 slice + Wih windows.
// All dot chains use 4 accumulators.
__global__ __launch_bounds__(512, 2)
void k_decoder(const float* __restrict__ kq_g, const float* __restrict__ vw_g,
               const float* __restrict__ cst_g,
               const float* __restrict__ W1,   const float* __restrict__ b1_g,
               const float* __restrict__ WihR, const float* __restrict__ WhhR,
               const float* __restrict__ bd_g,
               float* __restrict__ dec_out, float* __restrict__ attn_w) {
    const int b   = blockIdx.x;
    const int tid = threadIdx.x;

    __shared__ __align__(16) f4 kq_lds[Ln * 32];       // 128 KB, swizzled
    __shared__ __align__(16) float tok_s[D0n];
    __shared__ __align__(16) float x_s[Hn];
    __shared__ __align__(16) float h_s[Hn];
    __shared__ __align__(16) float g_s[H4n];
    __shared__ float s_s[Ln];
    __shared__ float attn_sp[8][33];                   // padded
    __shared__ float cst_s[Ln];
    __shared__ __align__(16) float b1_s[Hn];
    __shared__ float bd_s[H4n];

    // ---- persistent registers (pinned) ----
    f4 whr[32];                        // Whh row (f4-major layout, coalesced)
    const f4* WhhR4 = (const f4*)WhhR;
#pragma unroll
    for (int f = 0; f < 32; ++f) whr[f] = WhhR4[f * 512 + tid];
#pragma unroll
    for (int f = 0; f < 32; ++f) asm volatile("" : "+v"(whr[f]));

    const int o = tid >> 3, slab = tid & 7;            // phase-GH map
    float vwr[32];                                     // VW'[slab*32+l][o]
#pragma unroll
    for (int l = 0; l < 32; ++l)
        vwr[l] = vw_g[((size_t)b * Ln + slab * 32 + l) * D0n + o];
#pragma unroll
    for (int l = 0; l < 32; ++l) asm volatile("" : "+v"(vwr[l]));

    // ---- stage KQ into LDS with XOR swizzle (phys f4 = f ^ (l&7)) ----
    const f4* kq4 = (const f4*)(kq_g + (size_t)b * Ln * Hn);
#pragma unroll
    for (int it = 0; it < 16; ++it) {
        int idx = it * 512 + tid;
        int l = idx >> 5, f = idx & 31;
        kq_lds[l * 32 + (f ^ (l & 7))] = kq4[idx];
    }
    if (tid < D0n) tok_s[tid] = 0.f;
    if (tid < Hn)  { h_s[tid] = 0.f; b1_s[tid] = b1_g[tid]; }
    if (tid < Ln)  cst_s[tid] = cst_g[(size_t)b * Ln + tid];
    bd_s[tid] = bd_g[tid];
    float c_reg = 0.f;
    __syncthreads();

    const int arow = tid >> 2, apart = tid & 3;        // phase-A map
    const int el = tid >> 1, ep = tid & 1;             // phase-E map
    const f4* WihR4 = (const f4*)WihR;
    const f4* W1_4  = (const f4*)W1;

    for (int t = 0; t < Ln; ++t) {
        // opaque zero: stop LICM from hoisting per-step streamed loads
        int tz = 0;
        asm volatile("" : "+v"(tz));

        // issue W1 slice + first Wih window (latency covered by whh.h below)
        f4 w1r[4];
#pragma unroll
        for (int f = 0; f < 4; ++f) w1r[f] = W1_4[arow * 16 + apart * 4 + f + tz];
        f4 wb0[8], wb1[8];
#pragma unroll
        for (int k = 0; k < 8; ++k) wb0[k] = WihR4[k * 512 + tid + tz];

        // ---- early: accB = bd + Whh . h(t-1); 4 chains ----
        float aB0 = bd_s[tid], aB1 = 0.f, aB2 = 0.f, aB3 = 0.f;
        {
            const f4* h4 = (const f4*)h_s;
#pragma unroll
            for (int f = 0; f < 32; f += 4) {
                aB0 = fma4v(whr[f],     h4[f],     aB0);
                aB1 = fma4v(whr[f + 1], h4[f + 1], aB1);
                aB2 = fma4v(whr[f + 2], h4[f + 2], aB2);
                aB3 = fma4v(whr[f + 3], h4[f + 3], aB3);
            }
        }
        // ---- A: x = relu(W1 @ tok + b1); 128 rows x 4 parts, 2 chains ----
        {
            const f4* t4 = (const f4*)tok_s;
            float u0 = fma4v(w1r[0], t4[apart * 4],     0.f);
            float u1 = fma4v(w1r[1], t4[apart * 4 + 1], 0.f);
            u0 = fma4v(w1r[2], t4[apart * 4 + 2], u0);
            u1 = fma4v(w1r[3], t4[apart * 4 + 3], u1);
            float a = u0 + u1;
            a += __shfl_xor(a, 1);
            a += __shfl_xor(a, 2);
            if (apart == 0) x_s[arow] = fmaxf(a + b1_s[arow], 0.f);
        }
        __syncthreads();
        // ---- B: accB += Wih . x ; streamed windows, 4 chains ----
        {
            const f4* x4 = (const f4*)x_s;
#pragma unroll
            for (int k = 0; k < 8; ++k) wb1[k] = WihR4[(8 + k) * 512 + tid + tz];
            aB0 = fma4v(wb0[0], x4[0], aB0); aB1 = fma4v(wb0[1], x4[1], aB1);
            aB2 = fma4v(wb0[2], x4[2], aB2); aB3 = fma4v(wb0[3], x4[3], aB3);
            aB0 = fma4v(wb0[4], x4[4], aB0); aB1 = fma4v(wb0[5], x4[5], aB1);
            aB2 = fma4v(wb0[6], x4[6], aB2); aB3 = fma4v(wb0[7], x4[7], aB3);
#pragma unroll
            for (int k = 0; k < 8; ++k) wb0[k] = WihR4[(16 + k) * 512 + tid + tz];
            aB0 = fma4v(wb1[0], x4[8], aB0);  aB1 = fma4v(wb1[1], x4[9], aB1);
            aB2 = fma4v(wb1[2], x4[10], aB2); aB3 = fma4v(wb1[3], x4[11], aB3);
            aB0 = fma4v(wb1[4], x4[12], aB0); aB1 = fma4v(wb1[5], x4[13], aB1);
            aB2 = fma4v(wb1[6], x4[14], aB2); aB3 = fma4v(wb1[7], x4[15], aB3);
#pragma unroll
            for (int k = 0; k < 8; ++k) wb1[k] = WihR4[(24 + k) * 512 + tid + tz];
            aB0 = fma4v(wb0[0], x4[16], aB0); aB1 = fma4v(wb0[1], x4[17], aB1);
            aB2 = fma4v(wb0[2], x4[18], aB2); aB3 = fma4v(wb0[3], x4[19], aB3);
            aB0 = fma4v(wb0[4], x4[20], aB0); aB1 = fma4v(wb0[5], x4[21], aB1);
            aB2 = fma4v(wb0[6], x4[22], aB2); aB3 = fma4v(wb0[7], x4[23], aB3);
            aB0 = fma4v(wb1[0], x4[24], aB0); aB1 = fma4v(wb1[1], x4[25], aB1);
            aB2 = fma4v(wb1[2], x4[26], aB2); aB3 = fma4v(wb1[3], x4[27], aB3);
            aB0 = fma4v(wb1[4], x4[28], aB0); aB1 = fma4v(wb1[5], x4[29], aB1);
            aB2 = fma4v(wb1[6], x4[30], aB2); aB3 = fma4v(wb1[7], x4[31], aB3);
            g_s[tid] = (aB0 + aB1) + (aB2 + aB3);
        }
        __syncthreads();
        // ---- C: LSTM cell (threads 0..127) ----
        if (tid < Hn) {
            float ig = sigf(g_s[tid]);
            float fg = sigf(g_s[Hn + tid]);
            float gg = tanhf(g_s[2 * Hn + tid]);
            float og = sigf(g_s[3 * Hn + tid]);
            c_reg = fg * c_reg + ig * gg;
            h_s[tid] = og * tanhf(c_reg);
        }
        __syncthreads();
        // ---- E: s[l] = h . KQ[l] + cst[l]; 256 l x 2 parts, 4 chains ----
        {
            const f4* h4 = (const f4*)h_s;
            float e0 = 0.f, e1 = 0.f, e2 = 0.f, e3 = 0.f;
#pragma unroll
            for (int i = 0; i < 16; i += 4) {
                int f = ep * 16 + i;
                e0 = fma4v(kq_lds[el * 32 + ((f)     ^ (el & 7))], h4[f],     e0);
                e1 = fma4v(kq_lds[el * 32 + ((f + 1) ^ (el & 7))], h4[f + 1], e1);
                e2 = fma4v(kq_lds[el * 32 + ((f + 2) ^ (el & 7))], h4[f + 2], e2);
                e3 = fma4v(kq_lds[el * 32 + ((f + 3) ^ (el & 7))], h4[f + 3], e3);
            }
            float a = (e0 + e1) + (e2 + e3);
            a += __shfl_xor(a, 1);
            if (ep == 0) s_s[el] = a + cst_s[el];
        }
        __syncthreads();
        // ---- F: softmax, wave 0 only ----
        if (tid < 64) {
            float v0 = s_s[tid],       v1 = s_s[tid + 64];
            float v2 = s_s[tid + 128], v3 = s_s[tid + 192];
            float m = fmaxf(fmaxf(v0, v1), fmaxf(v2, v3));
#pragma unroll
            for (int o2 = 32; o2 > 0; o2 >>= 1) m = fmaxf(m, __shfl_xor(m, o2));
            float e0 = expf(v0 - m), e1 = expf(v1 - m);
            float e2 = expf(v2 - m), e3 = expf(v3 - m);
            float s = (e0 + e1) + (e2 + e3);
#pragma unroll
            for (int o2 = 32; o2 > 0; o2 >>= 1) s += __shfl_xor(s, o2);
            float inv = 1.f / s;
            e0 *= inv; e1 *= inv; e2 *= inv; e3 *= inv;
            attn_sp[tid >> 5][tid & 31] = e0;
            attn_sp[(tid + 64) >> 5][tid & 31] = e1;
            attn_sp[(tid + 128) >> 5][tid & 31] = e2;
            attn_sp[(tid + 192) >> 5][tid & 31] = e3;
            float* aw = attn_w + ((size_t)b * Ln + t) * Ln;
            aw[tid] = e0; aw[tid + 64] = e1;
            aw[tid + 128] = e2; aw[tid + 192] = e3;
        }
        __syncthreads();
        // ---- GH: out[o] = sum_l attn[l]*VW'[l][o]; 64 o x 8 slabs, 4 chains ----
        {
            const float* as = attn_sp[slab];
            float g0 = 0.f, g1 = 0.f, g2 = 0.f, g3 = 0.f;
#pragma unroll
            for (int l = 0; l < 32; l += 4) {
                g0 = fmaf(as[l],     vwr[l],     g0);
                g1 = fmaf(as[l + 1], vwr[l + 1], g1);
                g2 = fmaf(as[l + 2], vwr[l + 2], g2);
                g3 = fmaf(as[l + 3], vwr[l + 3], g3);
            }
            float a = (g0 + g1) + (g2 + g3);
            a += __shfl_xor(a, 1);
            a += __shfl_xor(a, 2);
            a += __shfl_xor(a, 4);
            if (slab == 0) {
                tok_s[o] = a;
                dec_out[((size_t)b * Ln + t) * D0n + o] = a;
            }
        }
        __syncthreads();
    }
}

extern "C" void kernel_launch(void* const* d_in, const int* in_sizes, int n_in,
                              void* d_out, int out_size, void* d_ws, size_t ws_size,
                              hipStream_t stream) {
    const float* inputs     = (const float*)d_in[0];
    const float* in_mask    = (const float*)d_in[2];
    const float* enc_lin1_W = (const float*)d_in[3];
    const float* enc_lin1_b = (const float*)d_in[4];
    const float* enc_Wih_f  = (const float*)d_in[5];
    const float* enc_Whh_f  = (const float*)d_in[6];
    const float* enc_b_f    = (const float*)d_in[7];
    const float* enc_Wih_b  = (const float*)d_in[8];
    const float* enc_Whh_b  = (const float*)d_in[9];
    const float* enc_b_b    = (const float*)d_in[10];
    const float* enc_lin2_W = (const float*)d_in[11];
    const float* enc_lin2_b = (const float*)d_in[12];
    const float* vq_emb     = (const float*)d_in[13];
    const float* dec_lin1_W = (const float*)d_in[14];
    const float* dec_lin1_b = (const float*)d_in[15];
    const float* dec_Wih    = (const float*)d_in[16];
    const float* dec_Whh    = (const float*)d_in[17];
    const float* dec_b      = (const float*)d_in[18];
    const float* attn_Wq    = (const float*)d_in[19];
    const float* attn_bq    = (const float*)d_in[20];
    const float* attn_Wk    = (const float*)d_in[21];
    const float* attn_bk    = (const float*)d_in[22];
    const float* attn_Wv    = (const float*)d_in[23];
    const float* attn_bv    = (const float*)d_in[24];
    const float* dec_lin2_W = (const float*)d_in[25];
    const float* dec_lin2_b = (const float*)d_in[26];

    float* out     = (float*)d_out;
    float* dec_out = out;                       // 16*256*64   = 262144
    float* attn_w  = out + 262144;              // 16*256*256  = 1048576
    float* ze      = out + 1310720;             // 16*256*128  = 524288
    float* zq      = out + 1835008;             // 16*256*128  = 524288

    float* ws    = (float*)d_ws;
    float* enc_x = ws;                          // 524288
    float* xWf   = enc_x + 524288;              // 2097152
    float* xWb   = xWf + 2097152;               // 2097152
    float* hf    = xWb + 2097152;               // 524288
    float* hb    = hf + 524288;                 // 524288
    float* kp    = hb + 524288;                 // 524288
    float* vp    = kp + 524288;                 // 524288
    float* c2    = vp + 524288;                 // 512
    // aliases into dead regions:
    float* kq    = xWf;                         // 524288  (xWf dead post-LSTM)
    float* vw    = xWb;                         // 262144  (xWb dead post-LSTM)
    float* cst   = xWb + 262144;                // 4096
    float* WqT   = hf;                          // 16384   (hf dead post-enc_lin2)
    float* WhhR  = hf + 16384;                  // 65536
    float* WihR  = hf + 16384 + 65536;          // 65536

    // ---- encoder ----
    k_lin<<<(BLn * Hn + 255) / 256, 256, 0, stream>>>(
        inputs, enc_lin1_W, enc_lin1_b, enc_x, BLn, D0n, Hn, 1, 1.f);
    k_lin<<<(BLn * H4n + 255) / 256, 256, 0, stream>>>(
        enc_x, enc_Wih_f, enc_b_f, xWf, BLn, Hn, H4n, 0, 1.f);
    k_lin<<<(BLn * H4n + 255) / 256, 256, 0, stream>>>(
        enc_x, enc_Wih_b, enc_b_b, xWb, BLn, Hn, H4n, 0, 1.f);
    k_lstm_scan<<<32, 1024, 0, stream>>>(xWf, xWb, enc_Whh_f, enc_Whh_b, hf, hb);
    k_enc_lin2<<<(BLn * Hn + 255) / 256, 256, 0, stream>>>(hf, hb, enc_lin2_W, enc_lin2_b, ze);
    // ---- weight rearrangements (into hf region, dead now) ----
    k_transpose<<<64, 256, 0, stream>>>(attn_Wq, WqT, Hn, Hn);
    k_rearr<<<64, 256, 0, stream>>>((const f4*)dec_Whh, (f4*)WhhR);
    k_rearr<<<64, 256, 0, stream>>>((const f4*)dec_Wih, (f4*)WihR);
    // ---- VQ ----
    k_codenorm<<<2, 256, 0, stream>>>(vq_emb, c2);
    k_vq<<<BLn, 256, 0, stream>>>(ze, vq_emb, c2, zq);
    // ---- attention precomputes (dec_in == zq) ----
    k_lin<<<(BLn * Hn + 255) / 256, 256, 0, stream>>>(zq, attn_Wk, attn_bk, kp, BLn, Hn, Hn, 0, 1.f);
    k_lin<<<(BLn * Hn + 255) / 256, 256, 0, stream>>>(zq, attn_Wv, attn_bv, vp, BLn, Hn, Hn, 0, 1.f);
    k_lin<<<(BLn * Hn + 255) / 256, 256, 0, stream>>>(
        kp, WqT, nullptr, kq, BLn, Hn, Hn, 0, 0.088388347648318447f);   // KQ = scale*Wq^T.kp
    k_lin<<<(BLn * D0n + 255) / 256, 256, 0, stream>>>(
        vp, dec_lin2_W, dec_lin2_b, vw, BLn, Hn, D0n, 0, 1.f);          // VW' = W2.vp + b2
    k_cst<<<Bn, 256, 0, stream>>>(kp, attn_bq, in_mask, cst);
    // ---- decoder ----
    k_decoder<<<Bn, 512, 0, stream>>>(kq, vw, cst,
                                      dec_lin1_W, dec_lin1_b,
                                      WihR, WhhR, dec_b,
                                      dec_out, attn_w);
}

// Round 5
// 2297.882 us; speedup vs baseline: 1.8897x; 1.8897x over previous
//
#include <hip/hip_runtime.h>

#define Bn  16
#define Ln  256
#define D0n 64
#define Hn  128
#define H4n 512
#define Kn  512
#define BLn 4096   // Bn*Ln

typedef float f4 __attribute__((ext_vector_type(4)));

__device__ __forceinline__ float sigf(float x) { return 1.0f / (1.0f + expf(-x)); }

__device__ __forceinline__ float fma4v(f4 w, f4 x, float acc) {
    acc = fmaf(w.x, x.x, acc);
    acc = fmaf(w.y, x.y, acc);
    acc = fmaf(w.z, x.z, acc);
    acc = fmaf(w.w, x.w, acc);
    return acc;
}

// ILP-4 dot product (n4 must be a multiple of 4)
__device__ __forceinline__ float dotn(const f4* __restrict__ a,
                                      const f4* __restrict__ w, int n4) {
    float a0 = 0.f, a1 = 0.f, a2 = 0.f, a3 = 0.f;
    for (int i = 0; i < n4; i += 4) {
        a0 = fma4v(a[i], w[i], a0);
        a1 = fma4v(a[i + 1], w[i + 1], a1);
        a2 = fma4v(a[i + 2], w[i + 2], a2);
        a3 = fma4v(a[i + 3], w[i + 3], a3);
    }
    return (a0 + a1) + (a2 + a3);
}

// -------- generic Linear: Y[r][c] = scale*(X[r].W[c]) + b[c], opt relu --------
__global__ void k_lin(const float* __restrict__ X, const float* __restrict__ W,
                      const float* __restrict__ b, float* __restrict__ Y,
                      int rows, int in_dim, int out_dim, int do_relu, float scale) {
    int idx = blockIdx.x * blockDim.x + threadIdx.x;
    if (idx >= rows * out_dim) return;
    int r = idx / out_dim, c = idx % out_dim;
    const f4* x4 = (const f4*)(X + (size_t)r * in_dim);
    const f4* w4 = (const f4*)(W + (size_t)c * in_dim);
    float acc = scale * dotn(x4, w4, in_dim >> 2);
    if (b) acc += b[c];
    if (do_relu) acc = fmaxf(acc, 0.f);
    Y[idx] = acc;
}

// -------- enc_lin2 with concatenated [hf, hb] input --------
__global__ void k_enc_lin2(const float* __restrict__ hf, const float* __restrict__ hb,
                           const float* __restrict__ W2, const float* __restrict__ b2,
                           float* __restrict__ ze) {
    int idx = blockIdx.x * blockDim.x + threadIdx.x;
    if (idx >= BLn * Hn) return;
    int r = idx / Hn, c = idx % Hn;
    const float* w = W2 + (size_t)c * (2 * Hn);
    float acc = b2[c];
    acc += dotn((const f4*)(hf + (size_t)r * Hn), (const f4*)w, Hn >> 2);
    acc += dotn((const f4*)(hb + (size_t)r * Hn), (const f4*)(w + Hn), Hn >> 2);
    ze[idx] = acc;
}

// -------- small transpose: out[c][r] = in[r][c] --------
__global__ void k_transpose(const float* __restrict__ in, float* __restrict__ out,
                            int R, int C) {
    int idx = blockIdx.x * blockDim.x + threadIdx.x;
    if (idx >= R * C) return;
    int c = idx / R, r = idx % R;
    out[idx] = in[(size_t)r * C + c];
}

// -------- rearrange gate weights [512][32]f4 -> RW[(s*16+f)*512+tid] ---------
// thread tid of side s holds half-row (tid&1) of row s*256+(tid>>1)
__global__ void k_rearrG(const f4* __restrict__ in, f4* __restrict__ out) {
    int idx = blockIdx.x * blockDim.x + threadIdx.x;   // 16384
    if (idx >= 16384) return;
    int s = idx >> 13, f = (idx >> 9) & 15, tid = idx & 511;
    out[idx] = in[((size_t)(s * 256 + (tid >> 1))) * 32 + (tid & 1) * 16 + f];
}

// -------- rearrange W1 [128][16]f4 -> W1R[f*512+tid], tid=(row<<2)|part ------
__global__ void k_rearrW1(const f4* __restrict__ in, f4* __restrict__ out) {
    int idx = blockIdx.x * blockDim.x + threadIdx.x;   // 2048
    if (idx >= 2048) return;
    int f = idx >> 9, tid = idx & 511;
    out[idx] = in[((size_t)(tid >> 2)) * 16 + (tid & 3) * 4 + f];
}

// -------- zero the handshake flags --------
__global__ void k_zero(int* __restrict__ p, int n) {
    int i = blockIdx.x * blockDim.x + threadIdx.x;
    if (i < n) p[i] = 0;
}

// -------- cst[p] = scale*(bq . kp[p]) + (mask[p]==0 ? -1e9 : 0) --------
__global__ void k_cst(const float* __restrict__ kp, const float* __restrict__ bq,
                      const float* __restrict__ mask, float* __restrict__ cst) {
    int p = blockIdx.x * blockDim.x + threadIdx.x;
    if (p >= BLn) return;
    float a = dotn((const f4*)bq, (const f4*)(kp + (size_t)p * Hn), Hn >> 2);
    cst[p] = a * 0.088388347648318447f + (mask[p] == 0.f ? -1e9f : 0.f);
}

// -------- LSTM scan: 1024 thr, 2 threads per gate row, pinned half-row Whh ----
__global__ __launch_bounds__(1024)
void k_lstm_scan(const float* __restrict__ xWf, const float* __restrict__ xWb,
                 const float* __restrict__ Whh_f, const float* __restrict__ Whh_b,
                 float* __restrict__ hf, float* __restrict__ hb) {
    const int b   = blockIdx.x & 15;
    const int rev = blockIdx.x >> 4;
    const int tid = threadIdx.x;          // 0..1023
    const int row  = tid >> 1;            // gate row 0..511
    const int half = tid & 1;             // which 64-elem half of h
    const float* xW  = rev ? xWb : xWf;
    const float* Whh = rev ? Whh_b : Whh_f;
    float*       ho  = rev ? hb  : hf;

    __shared__ __align__(16) float h_s[Hn];
    __shared__ __align__(16) float g_s[H4n];

    float c_reg = 0.f;
    if (tid < Hn) h_s[tid] = 0.f;

    f4 w[16];
    {
        const f4* p = (const f4*)(Whh + (size_t)row * Hn + half * 64);
#pragma unroll
        for (int i = 0; i < 16; ++i) w[i] = p[i];
#pragma unroll
        for (int i = 0; i < 16; ++i) asm volatile("" : "+v"(w[i]));
    }
    const int t0 = rev ? (Ln - 1) : 0;
    float xw_v = (half == 0) ? xW[((size_t)b * Ln + t0) * H4n + row] : 0.f;
    __syncthreads();

    for (int s = 0; s < Ln; ++s) {
        const int t = rev ? (Ln - 1 - s) : s;
        float xw_n = 0.f;
        if (half == 0 && s + 1 < Ln) {
            int tn = rev ? (Ln - 2 - s) : (s + 1);
            xw_n = xW[((size_t)b * Ln + tn) * H4n + row];
        }
        const f4* hh = (const f4*)(h_s + half * 64);
        float a0 = 0.f, a1 = 0.f, a2 = 0.f, a3 = 0.f;
#pragma unroll
        for (int i = 0; i < 16; i += 4) {
            a0 = fma4v(w[i], hh[i], a0);
            a1 = fma4v(w[i + 1], hh[i + 1], a1);
            a2 = fma4v(w[i + 2], hh[i + 2], a2);
            a3 = fma4v(w[i + 3], hh[i + 3], a3);
        }
        float acc = (a0 + a1) + (a2 + a3);
        acc += __shfl_xor(acc, 1);
        if (half == 0) g_s[row] = acc + xw_v;
        __syncthreads();
        if (tid < Hn) {
            float ig = sigf(g_s[tid]);
            float fg = sigf(g_s[Hn + tid]);
            float gg = tanhf(g_s[2 * Hn + tid]);
            float og = sigf(g_s[3 * Hn + tid]);
            c_reg = fg * c_reg + ig * gg;
            float hv = og * tanhf(c_reg);
            h_s[tid] = hv;
            ho[((size_t)b * Ln + t) * Hn + tid] = hv;
        }
        __syncthreads();
        xw_v = xw_n;
    }
}

// -------- codebook squared norms --------
__global__ void k_codenorm(const float* __restrict__ emb, float* __restrict__ c2) {
    int k = blockIdx.x * blockDim.x + threadIdx.x;
    if (k >= Kn) return;
    const f4* e4 = (const f4*)(emb + (size_t)k * Hn);
    float acc = 0.f;
    for (int i = 0; i < Hn / 4; ++i) {
        f4 v = e4[i];
        acc = fmaf(v.x, v.x, acc); acc = fmaf(v.y, v.y, acc);
        acc = fmaf(v.z, v.z, acc); acc = fmaf(v.w, v.w, acc);
    }
    c2[k] = acc;
}

// -------- VQ: argmin_k (||e_k||^2 - 2 ze.e_k), first-index tie-break --------
__global__ __launch_bounds__(256)
void k_vq(const float* __restrict__ ze, const float* __restrict__ emb,
          const float* __restrict__ c2, float* __restrict__ zq) {
    const int p = blockIdx.x;           // b*L + l
    const int tid = threadIdx.x;        // 256
    __shared__ __align__(16) float z_s[Hn];
    __shared__ float vals[256];
    __shared__ int   idxs[256];
    if (tid < Hn) z_s[tid] = ze[(size_t)p * Hn + tid];
    __syncthreads();

    float best = 3.0e38f; int bidx = 0;
    for (int k = tid; k < Kn; k += 256) {
        float d = c2[k] - 2.f * dotn((const f4*)z_s,
                                     (const f4*)(emb + (size_t)k * Hn), Hn >> 2);
        if (d < best) { best = d; bidx = k; }   // strict <  => first occurrence
    }
    vals[tid] = best; idxs[tid] = bidx;
    __syncthreads();
    for (int s = 128; s > 0; s >>= 1) {
        if (tid < s) {
            float v2 = vals[tid + s]; int i2 = idxs[tid + s];
            if (v2 < vals[tid] || (v2 == vals[tid] && i2 < idxs[tid])) {
                vals[tid] = v2; idxs[tid] = i2;
            }
        }
        __syncthreads();
    }
    const int nearest = idxs[0];
    if (tid < Hn) zq[(size_t)p * Hn + tid] = emb[(size_t)nearest * Hn + tid];
}

// -------- decoder: 2 blocks per batch, ALL weights resident, 1 handoff/step --
// side owns gate rows [side*256, side*256+256): side0={i,f}, side1={g~,o}.
// Pinned VGPRs/thread: Whh-half 64 + Wih-half 64 + W1 16 + VW 32. KQ in LDS.
// Per step: x -> gates(half) -> exchange halves (agent atomics + flag) ->
// cell -> scores -> softmax -> out.  Both sides compute cell/attn redundantly.
__global__ __launch_bounds__(512)
__attribute__((amdgpu_waves_per_eu(2, 2)))
void k_decoder(const float* __restrict__ kq_g, const float* __restrict__ vw_g,
               const float* __restrict__ cst_g,
               const float* __restrict__ W1R,  const float* __restrict__ b1_g,
               const float* __restrict__ WihR, const float* __restrict__ WhhR,
               const float* __restrict__ bd_g,
               float* gx, int* flags,
               float* __restrict__ dec_out, float* __restrict__ attn_w) {
    const int pair = blockIdx.x & 15;      // batch
    const int side = blockIdx.x >> 4;      // 0 or 1 (pair p and p+16 likely same XCD)
    const int b    = pair;
    const int tid  = threadIdx.x;

    __shared__ __align__(16) f4 kq_lds[Ln * 32];       // 128 KB, swizzled
    __shared__ __align__(16) float tok_s[D0n];
    __shared__ __align__(16) float x_s[Hn];
    __shared__ __align__(16) float h_s[Hn];
    __shared__ __align__(16) float g_all[H4n];
    __shared__ float s_s[Ln];
    __shared__ float attn_sp[8][33];
    __shared__ float cst_s[Ln];
    __shared__ __align__(16) float b1_s[Hn];

    // ---- pinned weights ----
    const f4* WhhR4 = (const f4*)WhhR;
    const f4* WihR4 = (const f4*)WihR;
    const f4* W1R4  = (const f4*)W1R;
    f4 whh[16], wih[16], w1r[4];
#pragma unroll
    for (int f = 0; f < 16; ++f) whh[f] = WhhR4[(side * 16 + f) * 512 + tid];
#pragma unroll
    for (int f = 0; f < 16; ++f) wih[f] = WihR4[(side * 16 + f) * 512 + tid];
#pragma unroll
    for (int f = 0; f < 4; ++f)  w1r[f] = W1R4[f * 512 + tid];
    float bdr = bd_g[side * 256 + (tid >> 1)];
    const int o = tid >> 3, slab = tid & 7;            // out phase map
    float vwr[32];
#pragma unroll
    for (int l = 0; l < 32; ++l)
        vwr[l] = vw_g[((size_t)b * Ln + slab * 32 + l) * D0n + o];
#pragma unroll
    for (int f = 0; f < 16; ++f) asm volatile("" : "+v"(whh[f]));
#pragma unroll
    for (int f = 0; f < 16; ++f) asm volatile("" : "+v"(wih[f]));
#pragma unroll
    for (int f = 0; f < 4; ++f)  asm volatile("" : "+v"(w1r[f]));
#pragma unroll
    for (int l = 0; l < 32; ++l) asm volatile("" : "+v"(vwr[l]));
    asm volatile("" : "+v"(bdr));

    // ---- stage KQ into LDS with XOR swizzle (phys f4 = f ^ (l&7)) ----
    const f4* kq4 = (const f4*)(kq_g + (size_t)b * Ln * Hn);
#pragma unroll
    for (int it = 0; it < 16; ++it) {
        int idx = it * 512 + tid;
        int l = idx >> 5, f = idx & 31;
        kq_lds[l * 32 + (f ^ (l & 7))] = kq4[idx];
    }
    if (tid < D0n) tok_s[tid] = 0.f;
    if (tid < Hn)  { h_s[tid] = 0.f; b1_s[tid] = b1_g[tid]; }
    if (tid < Ln)  cst_s[tid] = cst_g[(size_t)b * Ln + tid];
    float c_reg = 0.f;
    __syncthreads();

    float* gx_mine = gx + ((b * 2 + side) * 2) * 256;
    float* gx_peer = gx + ((b * 2 + (side ^ 1)) * 2) * 256;
    int* flag_mine = flags + (b * 2 + side);
    int* flag_peer = flags + (b * 2 + (side ^ 1));

    const int arow = tid >> 2, apart = tid & 3;        // x phase map
    const int el = tid >> 1, ep = tid & 1;             // score phase map
    const int grow = tid >> 1, ghalf = tid & 1;        // gate phase map

    for (int t = 0; t < Ln; ++t) {
        // ---- A: x = relu(W1 @ tok + b1); 128 rows x 4 parts ----
        {
            const f4* t4 = (const f4*)tok_s;
            float u0 = fma4v(w1r[0], t4[apart * 4],     0.f);
            float u1 = fma4v(w1r[1], t4[apart * 4 + 1], 0.f);
            u0 = fma4v(w1r[2], t4[apart * 4 + 2], u0);
            u1 = fma4v(w1r[3], t4[apart * 4 + 3], u1);
            float a = u0 + u1;
            a += __shfl_xor(a, 1);
            a += __shfl_xor(a, 2);
            if (apart == 0) x_s[arow] = fmaxf(a + b1_s[arow], 0.f);
        }
        __syncthreads();
        // ---- gates (own half): 256 rows x 2 threads, pinned weights ----
        {
            const f4* x4 = (const f4*)x_s;
            const f4* h4 = (const f4*)h_s;
            const int base = ghalf * 16;
            float a0 = 0.f, a1 = 0.f, a2 = 0.f, a3 = 0.f;
#pragma unroll
            for (int f = 0; f < 16; f += 4) {
                a0 = fma4v(wih[f],     x4[base + f],     a0);
                a1 = fma4v(wih[f + 1], x4[base + f + 1], a1);
                a2 = fma4v(wih[f + 2], x4[base + f + 2], a2);
                a3 = fma4v(wih[f + 3], x4[base + f + 3], a3);
            }
#pragma unroll
            for (int f = 0; f < 16; f += 4) {
                a0 = fma4v(whh[f],     h4[base + f],     a0);
                a1 = fma4v(whh[f + 1], h4[base + f + 1], a1);
                a2 = fma4v(whh[f + 2], h4[base + f + 2], a2);
                a3 = fma4v(whh[f + 3], h4[base + f + 3], a3);
            }
            float a = (a0 + a1) + (a2 + a3);
            a += __shfl_xor(a, 1);
            if (ghalf == 0) {
                float gval = a + bdr;
                g_all[side * 256 + grow] = gval;
                __hip_atomic_store(&gx_mine[(t & 1) * 256 + grow], gval,
                                   __ATOMIC_RELAXED, __HIP_MEMORY_SCOPE_AGENT);
            }
        }
        __syncthreads();   // drains vmcnt: all gx stores complete
        if (tid == 0) {
            __hip_atomic_store(flag_mine, t + 1, __ATOMIC_RELEASE, __HIP_MEMORY_SCOPE_AGENT);
            while (__hip_atomic_load(flag_peer, __ATOMIC_ACQUIRE, __HIP_MEMORY_SCOPE_AGENT) < t + 1) {}
        }
        __syncthreads();
        if (tid < 256)
            g_all[(side ^ 1) * 256 + tid] =
                __hip_atomic_load(&gx_peer[(t & 1) * 256 + tid],
                                  __ATOMIC_RELAXED, __HIP_MEMORY_SCOPE_AGENT);
        __syncthreads();
        // ---- cell (threads 0..127), both sides redundantly ----
        if (tid < Hn) {
            float ig = sigf(g_all[tid]);
            float fg = sigf(g_all[Hn + tid]);
            float gg = tanhf(g_all[2 * Hn + tid]);
            float og = sigf(g_all[3 * Hn + tid]);
            c_reg = fg * c_reg + ig * gg;
            h_s[tid] = og * tanhf(c_reg);
        }
        __syncthreads();
        // ---- scores: s[l] = h . KQ[l] + cst[l]; 256 l x 2 parts ----
        {
            const f4* h4 = (const f4*)h_s;
            float e0 = 0.f, e1 = 0.f, e2 = 0.f, e3 = 0.f;
#pragma unroll
            for (int i = 0; i < 16; i += 4) {
                int f = ep * 16 + i;
                e0 = fma4v(kq_lds[el * 32 + ((f)     ^ (el & 7))], h4[f],     e0);
                e1 = fma4v(kq_lds[el * 32 + ((f + 1) ^ (el & 7))], h4[f + 1], e1);
                e2 = fma4v(kq_lds[el * 32 + ((f + 2) ^ (el & 7))], h4[f + 2], e2);
                e3 = fma4v(kq_lds[el * 32 + ((f + 3) ^ (el & 7))], h4[f + 3], e3);
            }
            float a = (e0 + e1) + (e2 + e3);
            a += __shfl_xor(a, 1);
            if (ep == 0) s_s[el] = a + cst_s[el];
        }
        __syncthreads();
        // ---- softmax, wave 0 only; side 0 writes attn_w ----
        if (tid < 64) {
            float v0 = s_s[tid],       v1 = s_s[tid + 64];
            float v2 = s_s[tid + 128], v3 = s_s[tid + 192];
            float m = fmaxf(fmaxf(v0, v1), fmaxf(v2, v3));
#pragma unroll
            for (int o2 = 32; o2 > 0; o2 >>= 1) m = fmaxf(m, __shfl_xor(m, o2));
            float e0 = expf(v0 - m), e1 = expf(v1 - m);
            float e2 = expf(v2 - m), e3 = expf(v3 - m);
            float s = (e0 + e1) + (e2 + e3);
#pragma unroll
            for (int o2 = 32; o2 > 0; o2 >>= 1) s += __shfl_xor(s, o2);
            float inv = 1.f / s;
            e0 *= inv; e1 *= inv; e2 *= inv; e3 *= inv;
            attn_sp[tid >> 5][tid & 31] = e0;
            attn_sp[(tid + 64) >> 5][tid & 31] = e1;
            attn_sp[(tid + 128) >> 5][tid & 31] = e2;
            attn_sp[(tid + 192) >> 5][tid & 31] = e3;
            if (side == 0) {
                float* aw = attn_w + ((size_t)b * Ln + t) * Ln;
                aw[tid] = e0; aw[tid + 64] = e1;
                aw[tid + 128] = e2; aw[tid + 192] = e3;
            }
        }
        __syncthreads();
        // ---- out[o] = sum_l attn[l]*VW'[l][o]; 64 o x 8 slabs ----
        {
            const float* as = attn_sp[slab];
            float g0 = 0.f, g1 = 0.f, g2 = 0.f, g3 = 0.f;
#pragma unroll
            for (int l = 0; l < 32; l += 4) {
                g0 = fmaf(as[l],     vwr[l],     g0);
                g1 = fmaf(as[l + 1], vwr[l + 1], g1);
                g2 = fmaf(as[l + 2], vwr[l + 2], g2);
                g3 = fmaf(as[l + 3], vwr[l + 3], g3);
            }
            float a = (g0 + g1) + (g2 + g3);
            a += __shfl_xor(a, 1);
            a += __shfl_xor(a, 2);
            a += __shfl_xor(a, 4);
            if (slab == 0) {
                tok_s[o] = a;
                if (side == 1) dec_out[((size_t)b * Ln + t) * D0n + o] = a;
            }
        }
        __syncthreads();
    }
}

extern "C" void kernel_launch(void* const* d_in, const int* in_sizes, int n_in,
                              void* d_out, int out_size, void* d_ws, size_t ws_size,
                              hipStream_t stream) {
    const float* inputs     = (const float*)d_in[0];
    const float* in_mask    = (const float*)d_in[2];
    const float* enc_lin1_W = (const float*)d_in[3];
    const float* enc_lin1_b = (const float*)d_in[4];
    const float* enc_Wih_f  = (const float*)d_in[5];
    const float* enc_Whh_f  = (const float*)d_in[6];
    const float* enc_b_f    = (const float*)d_in[7];
    const float* enc_Wih_b  = (const float*)d_in[8];
    const float* enc_Whh_b  = (const float*)d_in[9];
    const float* enc_b_b    = (const float*)d_in[10];
    const float* enc_lin2_W = (const float*)d_in[11];
    const float* enc_lin2_b = (const float*)d_in[12];
    const float* vq_emb     = (const float*)d_in[13];
    const float* dec_lin1_W = (const float*)d_in[14];
    const float* dec_lin1_b = (const float*)d_in[15];
    const float* dec_Wih    = (const float*)d_in[16];
    const float* dec_Whh    = (const float*)d_in[17];
    const float* dec_b      = (const float*)d_in[18];
    const float* attn_Wq    = (const float*)d_in[19];
    const float* attn_bq    = (const float*)d_in[20];
    const float* attn_Wk    = (const float*)d_in[21];
    const float* attn_bk    = (const float*)d_in[22];
    const float* attn_Wv    = (const float*)d_in[23];
    const float* attn_bv    = (const float*)d_in[24];
    const float* dec_lin2_W = (const float*)d_in[25];
    const float* dec_lin2_b = (const float*)d_in[26];

    float* out     = (float*)d_out;
    float* dec_out = out;                       // 16*256*64   = 262144
    float* attn_w  = out + 262144;              // 16*256*256  = 1048576
    float* ze      = out + 1310720;             // 16*256*128  = 524288
    float* zq      = out + 1835008;             // 16*256*128  = 524288

    float* ws    = (float*)d_ws;
    float* enc_x = ws;                          // 524288
    float* xWf   = enc_x + 524288;              // 2097152
    float* xWb   = xWf + 2097152;               // 2097152
    float* hf    = xWb + 2097152;               // 524288
    float* hb    = hf + 524288;                 // 524288
    float* kp    = hb + 524288;                 // 524288
    float* vp    = kp + 524288;                 // 524288
    float* c2    = vp + 524288;                 // 512
    float* gxbuf = c2 + 512;                    // 16*2*2*256 = 16384
    int*   flags = (int*)(gxbuf + 16384);       // 32 ints
    // aliases into dead regions:
    float* kq    = xWf;                         // 524288  (xWf dead post-LSTM)
    float* vw    = xWb;                         // 262144  (xWb dead post-LSTM)
    float* cst   = xWb + 262144;                // 4096
    float* WqT   = hf;                          // 16384   (hf dead post-enc_lin2)
    float* WhhR  = hf + 16384;                  // 65536
    float* WihR  = hf + 16384 + 65536;          // 65536
    float* W1R   = hf + 16384 + 65536 + 65536;  // 8192

    // ---- encoder ----
    k_lin<<<(BLn * Hn + 255) / 256, 256, 0, stream>>>(
        inputs, enc_lin1_W, enc_lin1_b, enc_x, BLn, D0n, Hn, 1, 1.f);
    k_lin<<<(BLn * H4n + 255) / 256, 256, 0, stream>>>(
        enc_x, enc_Wih_f, enc_b_f, xWf, BLn, Hn, H4n, 0, 1.f);
    k_lin<<<(BLn * H4n + 255) / 256, 256, 0, stream>>>(
        enc_x, enc_Wih_b, enc_b_b, xWb, BLn, Hn, H4n, 0, 1.f);
    k_lstm_scan<<<32, 1024, 0, stream>>>(xWf, xWb, enc_Whh_f, enc_Whh_b, hf, hb);
    k_enc_lin2<<<(BLn * Hn + 255) / 256, 256, 0, stream>>>(hf, hb, enc_lin2_W, enc_lin2_b, ze);
    // ---- weight rearrangements (into hf region, dead now) ----
    k_transpose<<<64, 256, 0, stream>>>(attn_Wq, WqT, Hn, Hn);
    k_rearrG<<<32, 512, 0, stream>>>((const f4*)dec_Whh, (f4*)WhhR);
    k_rearrG<<<32, 512, 0, stream>>>((const f4*)dec_Wih, (f4*)WihR);
    k_rearrW1<<<4, 512, 0, stream>>>((const f4*)dec_lin1_W, (f4*)W1R);
    k_zero<<<1, 64, 0, stream>>>(flags, 32);
    // ---- VQ ----
    k_codenorm<<<2, 256, 0, stream>>>(vq_emb, c2);
    k_vq<<<BLn, 256, 0, stream>>>(ze, vq_emb, c2, zq);
    // ---- attention precomputes (dec_in == zq) ----
    k_lin<<<(BLn * Hn + 255) / 256, 256, 0, stream>>>(zq, attn_Wk, attn_bk, kp, BLn, Hn, Hn, 0, 1.f);
    k_lin<<<(BLn * Hn + 255) / 256, 256, 0, stream>>>(zq, attn_Wv, attn_bv, vp, BLn, Hn, Hn, 0, 1.f);
    k_lin<<<(BLn * Hn + 255) / 256, 256, 0, stream>>>(
        kp, WqT, nullptr, kq, BLn, Hn, Hn, 0, 0.088388347648318447f);   // KQ = scale*Wq^T.kp
    k_lin<<<(BLn * D0n + 255) / 256, 256, 0, stream>>>(
        vp, dec_lin2_W, dec_lin2_b, vw, BLn, Hn, D0n, 0, 1.f);          // VW' = W2.vp + b2
    k_cst<<<Bn, 256, 0, stream>>>(kp, attn_bq, in_mask, cst);
    // ---- decoder: 32 blocks = 16 batches x 2 sides ----
    k_decoder<<<32, 512, 0, stream>>>(kq, vw, cst,
                                      W1R, dec_lin1_b,
                                      WihR, WhhR, dec_b,
                                      gxbuf, flags,
                                      dec_out, attn_w);
}